// Round 5
// baseline (190.083 us; speedup 1.0000x reference)
//
#include <hip/hip_runtime.h>

// SDPA B=2 H=16 S=2048 D=64 fp32. Two kernels.
//  prep: K,V -> fp16 in MFMA lane-order fragment layout (+ per-tile fp32 V
//        column sums Vpart); mask -> additive bias (-C2 / -1e30).
//  main: flash attention, fp16 MFMA, per-wave LDS double-buffer filled by
//        global_load_lds DMA.
//        R4 lesson: 1-step DMA slack + sched_barrier walls + step-top LDS
//        reads left ~600 cyc/step-pair of dual-pipe idle (MfmaUtil 25,
//        VALUBusy 34, dur 55.5us ~= R0).
//        R5 schedule: K-half and V-half of each buffer staged SEPARATELY,
//        each right after its half is consumed -> stage-to-use slack ~2
//        half-steps; counted waits vmcnt(16)/vmcnt(14) (never 0 in-loop);
//        NO sched_barriers (zero-cost asm memory walls only -- the vmcnt
//        region-sum counting is robust to in-region reordering);
//        LDK before QK / LDV before PV (V ds-latency hides under exp);
//        s_setprio(1) around PV MFMA cluster; bias fed directly as MFMA C
//        operand (no acc-init movs).
//        Geometry: 1024 blocks x 2 waves, wave = 64q x 1024 keys (K-split 2).
// Numerics: Q*scale*log2e folded in, fp16 QK, bias preloaded in accumulator,
// raw v_exp_f32, v_cvt_pkrtz pack, L via VALU adds. Masked query -> out =
// Vsum/2048 from fp32 Vpart (reference's uniform-softmax branch).

#define Bb 2
#define Hh 16
#define Ss 2048
#define Dd 64

typedef __attribute__((ext_vector_type(8))) _Float16 f16x8;
typedef __attribute__((ext_vector_type(2))) __fp16 fp16x2;
typedef __attribute__((ext_vector_type(4))) float f32x4;

#define C2F (4.0f * 1.44269504088896340736f)
#define SCLF (0.125f * 1.44269504088896340736f)   // folded into Q

// ---------------- prepass ----------------
// Kf frag: id=((bh*32+kt)*8+slot)*64+lane, slot=T*2+c, lane=rl|(g<<4):
//   elem j = K[bh][kt*64+T*16+rl][c*32+g*8+j]
// Vf frag: slot=G*4+n, lane=m|(g<<4):
//   elem j = V[bh][kt*64+G*32+((j>>2)&1)*16+g*4+(j&3)][n*16+m]
__global__ __launch_bounds__(256) void prep_kernel(
    const float* __restrict__ K, const float* __restrict__ V,
    const int* __restrict__ mask,
    ushort* __restrict__ Kf, ushort* __restrict__ Vf,
    float* __restrict__ mb, float* __restrict__ Vpart)
{
    __shared__ ushort tile[4096];
    __shared__ float  part[16][64];
    const int t = threadIdx.x;
    const int blk = blockIdx.x;

    if (blk < 1024) {                       // ---- K tiles (LDS-staged, coalesced) ----
        const int bh = blk >> 5, kt = blk & 31;
        const float* base = K + ((size_t)bh * Ss + kt * 64) * Dd;
        #pragma unroll
        for (int i = 0; i < 4; ++i) {
            const int p  = i * 16 + (t >> 4);
            const int c0 = (t & 15) * 4;
            const float4 f = *(const float4*)(base + (size_t)p * Dd + c0);
            const int T = p >> 4, rl = p & 15;
            const int c = c0 >> 5, g = (c0 & 31) >> 3, j0 = c0 & 7;
            union { _Float16 h[4]; uint2 d; } pk;
            pk.h[0] = (_Float16)f.x; pk.h[1] = (_Float16)f.y;
            pk.h[2] = (_Float16)f.z; pk.h[3] = (_Float16)f.w;
            *(uint2*)&tile[((T * 2 + c) * 64 + (rl | (g << 4))) * 8 + j0] = pk.d;
        }
        __syncthreads();
        uint4* dst = (uint4*)(Kf + (size_t)(bh * 32 + kt) * 4096);
        const uint4* src = (const uint4*)tile;
        dst[t] = src[t]; dst[t + 256] = src[t + 256];
    } else if (blk < 2048) {                // ---- V tiles: register transpose + Vpart ----
        const int bv = blk - 1024;
        const int bh = bv >> 5, kt = bv & 31;
        const float* base = V + ((size_t)bh * Ss + kt * 64) * Dd;
        const int kb4 = (t >> 4) * 4;       // key base 0..60
        const int d0  = (t & 15) * 4;       // d base   0..60 (consecutive t -> coalesced)
        const float4 r0 = *(const float4*)(base + (size_t)(kb4 + 0) * Dd + d0);
        const float4 r1 = *(const float4*)(base + (size_t)(kb4 + 1) * Dd + d0);
        const float4 r2 = *(const float4*)(base + (size_t)(kb4 + 2) * Dd + d0);
        const float4 r3 = *(const float4*)(base + (size_t)(kb4 + 3) * Dd + d0);
        const int G = kb4 >> 5, p5 = kb4 & 31;
        const int tt = p5 >> 4, g = (p5 >> 2) & 3;
        const int j0 = tt * 4;
        const int n = d0 >> 4, m0 = d0 & 15;
        ushort* dstb = Vf + (size_t)(bh * 32 + kt) * 4096;
        const float ra[4][4] = {{r0.x, r1.x, r2.x, r3.x}, {r0.y, r1.y, r2.y, r3.y},
                                {r0.z, r1.z, r2.z, r3.z}, {r0.w, r1.w, r2.w, r3.w}};
        float4 ps;
        #pragma unroll
        for (int dd = 0; dd < 4; ++dd) {
            union { _Float16 h[4]; uint2 d; } pk;
            pk.h[0] = (_Float16)ra[dd][0]; pk.h[1] = (_Float16)ra[dd][1];
            pk.h[2] = (_Float16)ra[dd][2]; pk.h[3] = (_Float16)ra[dd][3];
            const int lane = (m0 + dd) | (g << 4);
            *(uint2*)&dstb[((G * 4 + n) * 64 + lane) * 8 + j0] = pk.d;
            ((float*)&ps)[dd] = (ra[dd][0] + ra[dd][1]) + (ra[dd][2] + ra[dd][3]);
        }
        *(float4*)&part[t >> 4][d0] = ps;   // fp32 partial column sums (4 keys)
        __syncthreads();
        if (t < 64) {
            float acc = 0.f;
            #pragma unroll
            for (int gg = 0; gg < 16; ++gg) acc += part[gg][t];
            Vpart[(size_t)(bh * 32 + kt) * 64 + t] = acc;
        }
    } else {                                // ---- mask -> bias ----
        #pragma unroll
        for (int i = 0; i < 16; ++i) {
            const int idx = i * 256 + t;
            mb[idx] = mask[idx] ? (-C2F) : -1e30f;
        }
    }
}

// async 16B/lane global->LDS (lane l writes ldsbase + l*16, matching frag order)
static __device__ __forceinline__ void gll16(const void* g, ushort* l) {
    __builtin_amdgcn_global_load_lds(
        (const __attribute__((address_space(1))) void*)g,
        (__attribute__((address_space(3))) void*)l, 16, 0, 0);
}

// ---------------- main (split-staged LDS-DMA pipeline) ----------------
__global__ __launch_bounds__(128, 2) void sdpa_main(
    const float* __restrict__ Q, const ushort* __restrict__ Kf,
    const ushort* __restrict__ Vf, const float* __restrict__ mbp,
    const float* __restrict__ Vpart,
    const int* __restrict__ mask, float* __restrict__ out)
{
    // per-wave 2-deep staging: [wave][buf][K 4KB | V 4KB] = 32 KB total.
    // epilogue combine buffer (17.4 KB) aliases it (all DMA drained by then).
    __shared__ ushort sbuf[2][2][4096];
    float* comb = (float*)&sbuf[0][0][0];

    const int t  = threadIdx.x, w = t >> 6, l = t & 63;
    const int lq = l & 15, lg = l >> 4;
    const int bh = blockIdx.x & 31;         // XCD swizzle: one bh -> one L2
    const int qb = blockIdx.x >> 5;         // 0..31
    const int b  = bh >> 4;
    const int q0 = qb * 64;
    const int key0 = w * 1024;              // K-split 2: wave's key range

    const size_t bhS = (size_t)bh * Ss;
    const ushort* kgb = Kf + (size_t)(bh * 32) * 4096;
    const ushort* vgb = Vf + (size_t)(bh * 32) * 4096;
    const float*  mbb = mbp + b * Ss;

    // ---- Q fragments: 4 subtiles, fp16, scale*log2e folded ----
    f16x8 qh[4][2];
    #pragma unroll
    for (int s = 0; s < 4; ++s) {
        const float* qrow = Q + (bhS + q0 + s * 16 + lq) * Dd + lg * 8;
        #pragma unroll
        for (int c = 0; c < 2; ++c) {
            const float4 f0 = *(const float4*)(qrow + 32 * c);
            const float4 f1 = *(const float4*)(qrow + 32 * c + 4);
            const float qf[8] = {f0.x, f0.y, f0.z, f0.w, f1.x, f1.y, f1.z, f1.w};
            union { _Float16 h[8]; f16x8 v; } pk;
            #pragma unroll
            for (int j = 0; j < 8; ++j) pk.h[j] = (_Float16)(qf[j] * SCLF);
            qh[s][c] = pk.v;
        }
    }

    f32x4 Oacc[4][4];
    float lacc[4] = {0.f, 0.f, 0.f, 0.f};
    #pragma unroll
    for (int s = 0; s < 4; ++s)
        #pragma unroll
        for (int n = 0; n < 4; ++n) Oacc[s][n] = f32x4{0.f, 0.f, 0.f, 0.f};

    // ---- ordering primitives: zero-cost walls + counted waits (no sched_barrier) ----
    #define WALL    asm volatile("" ::: "memory")
    #define WVC(n)  asm volatile("s_waitcnt vmcnt(" #n ")" ::: "memory")
    #define WL0     asm volatile("s_waitcnt lgkmcnt(0)" ::: "memory")

    // stage HALF a key-step: 4 x global_load_lds (4 KB), K and V independent
    #define STG_K(kk, bufsel) do {                                              \
        const char* kc_ = (const char*)kgb + (size_t)(kk) * 128 + l * 16;       \
        ushort* lb_ = &sbuf[w][bufsel][0];                                      \
        gll16(kc_,        lb_);                                                 \
        gll16(kc_ + 1024, lb_ + 512);                                           \
        gll16(kc_ + 2048, lb_ + 1024);                                          \
        gll16(kc_ + 3072, lb_ + 1536);                                          \
    } while (0)
    #define STG_V(kk, bufsel) do {                                              \
        const char* vc_ = (const char*)vgb + (size_t)(kk) * 128 + l * 16;       \
        ushort* lb_ = &sbuf[w][bufsel][2048];                                   \
        gll16(vc_,        lb_);                                                 \
        gll16(vc_ + 1024, lb_ + 512);                                           \
        gll16(vc_ + 2048, lb_ + 1024);                                          \
        gll16(vc_ + 3072, lb_ + 1536);                                          \
    } while (0)

    #define BIAS(kk, B0, B1) do {                                               \
        B0 = *(const float4*)(mbb + (kk) + lg * 4);                             \
        B1 = *(const float4*)(mbb + (kk) + 16 + lg * 4);                        \
    } while (0)

    #define LDK(bufsel, KF) do {                                                \
        const ushort* p_ = &sbuf[w][bufsel][l * 8];                             \
        KF[0] = *(const f16x8*)(p_);                                            \
        KF[1] = *(const f16x8*)(p_ + 512);                                      \
        KF[2] = *(const f16x8*)(p_ + 1024);                                     \
        KF[3] = *(const f16x8*)(p_ + 1536);                                     \
    } while (0)
    #define LDV(bufsel, VF) do {                                                \
        const ushort* p_ = &sbuf[w][bufsel][2048 + l * 8];                      \
        VF[0] = *(const f16x8*)(p_);                                            \
        VF[1] = *(const f16x8*)(p_ + 512);                                      \
        VF[2] = *(const f16x8*)(p_ + 1024);                                     \
        VF[3] = *(const f16x8*)(p_ + 1536);                                     \
    } while (0)

    // QK (bias fed straight into the MFMA C operand) -> exp -> L -> pack
    #define QKEXP(KF, B0, B1, P8) do {                                          \
        _Pragma("unroll")                                                       \
        for (int T_ = 0; T_ < 2; ++T_) {                                        \
            const f16x8 k0_ = KF[T_ * 2], k1_ = KF[T_ * 2 + 1];                 \
            const float4 bi_ = (T_ == 0) ? B0 : B1;                             \
            _Pragma("unroll")                                                   \
            for (int s_ = 0; s_ < 4; ++s_) {                                    \
                f32x4 sc_ = __builtin_amdgcn_mfma_f32_16x16x32_f16(             \
                    k0_, qh[s_][0], (f32x4){bi_.x, bi_.y, bi_.z, bi_.w}, 0, 0, 0); \
                sc_ = __builtin_amdgcn_mfma_f32_16x16x32_f16(k1_, qh[s_][1], sc_, 0, 0, 0); \
                const float e0_ = __builtin_amdgcn_exp2f(sc_[0]);               \
                const float e1_ = __builtin_amdgcn_exp2f(sc_[1]);               \
                const float e2_ = __builtin_amdgcn_exp2f(sc_[2]);               \
                const float e3_ = __builtin_amdgcn_exp2f(sc_[3]);               \
                lacc[s_] += (e0_ + e1_) + (e2_ + e3_);                          \
                union { fp16x2 h; uint u; } pa_, pb_;                           \
                pa_.h = __builtin_amdgcn_cvt_pkrtz(e0_, e1_);                   \
                pb_.h = __builtin_amdgcn_cvt_pkrtz(e2_, e3_);                   \
                P8[s_].u32[T_ * 2]     = pa_.u;                                 \
                P8[s_].u32[T_ * 2 + 1] = pb_.u;                                 \
            }                                                                   \
        }                                                                       \
    } while (0)

    #define PVS(P8, VF) do {                                                    \
        __builtin_amdgcn_s_setprio(1);                                          \
        _Pragma("unroll")                                                       \
        for (int n_ = 0; n_ < 4; ++n_) {                                        \
            const f16x8 vf_ = VF[n_];                                           \
            _Pragma("unroll")                                                   \
            for (int s_ = 0; s_ < 4; ++s_)                                      \
                Oacc[s_][n_] = __builtin_amdgcn_mfma_f32_16x16x32_f16(P8[s_].v, vf_, Oacc[s_][n_], 0, 0, 0); \
        }                                                                       \
        __builtin_amdgcn_s_setprio(0);                                          \
    } while (0)

    union p8u { uint u32[4]; f16x8 v; };
    f16x8 kA[4], vA[4], kB[4], vB[4];
    p8u pA[4], pB[4];
    float4 a0, a1, b0, b1;

    // ---- prologue: stage tiles key0 (buf0) and key0+32 (buf1), load biases ----
    // vmem issue groups (walls pin group membership; counts are group-sums):
    // [K(t0) 4][V(t0) 4, b(t0) 2][K(t0+32) 4][V(t0+32) 4, b(t0+32) 2]
    STG_K(key0, 0);                       WALL;
    STG_V(key0, 0);  BIAS(key0, a0, a1); WALL;
    STG_K(key0 + 32, 1);                  WALL;
    STG_V(key0 + 32, 1); BIAS(key0 + 32, b0, b1);

    // ---- K-loop: per half-step {wait16, LDK, QK, stage-K | wait14, LDV, PV, stage-V+bias}
    // steady-state: ops-after-K(x) = 16 exact; ops-after-V(x) >= 14. DMA slack
    // for each half = ~2 half-steps; vmcnt never drains to 0 in-loop.
    for (int j = 0; j < 15; ++j) {
        const int tA = key0 + j * 64;
        // tile tA (buf0)
        WVC(16); LDK(0, kA);
        QKEXP(kA, a0, a1, pA);
        WL0; STG_K(tA + 64, 0);
        WVC(14); LDV(0, vA);
        PVS(pA, vA);
        WL0; STG_V(tA + 64, 0); BIAS(tA + 64, a0, a1);
        // tile tA+32 (buf1)
        WVC(16); LDK(1, kB);
        QKEXP(kB, b0, b1, pB);
        WL0; STG_K(tA + 96, 1);
        WVC(14); LDV(1, vB);
        PVS(pB, vB);
        WL0; STG_V(tA + 96, 1); BIAS(tA + 96, b0, b1);
    }
    // ---- tail: tiles key0+960 (buf0), key0+992 (buf1); no further stages ----
    WVC(16); LDK(0, kA);
    QKEXP(kA, a0, a1, pA);
    WVC(10); LDV(0, vA);
    PVS(pA, vA);
    WVC(6);  LDK(1, kB);
    QKEXP(kB, b0, b1, pB);
    WVC(0);  LDV(1, vB);
    PVS(pB, vB);

    #undef WALL
    #undef WVC
    #undef WL0
    #undef STG_K
    #undef STG_V
    #undef BIAS
    #undef LDK
    #undef LDV
    #undef QKEXP
    #undef PVS

    // ---- K-split combine (wave 1 -> LDS, wave 0 adds) + epilogue ----
    __syncthreads();
    if (w == 1) {
        int idx = 0;
        #pragma unroll
        for (int s = 0; s < 4; ++s)
            #pragma unroll
            for (int n = 0; n < 4; ++n)
                #pragma unroll
                for (int r = 0; r < 4; ++r) comb[(idx++) * 64 + l] = Oacc[s][n][r];
        #pragma unroll
        for (int s = 0; s < 4; ++s) comb[(64 + s) * 64 + l] = lacc[s];
    }
    __syncthreads();
    if (w == 0) {
        int idx = 0;
        #pragma unroll
        for (int s = 0; s < 4; ++s)
            #pragma unroll
            for (int n = 0; n < 4; ++n)
                #pragma unroll
                for (int r = 0; r < 4; ++r) Oacc[s][n][r] += comb[(idx++) * 64 + l];
        #pragma unroll
        for (int s = 0; s < 4; ++s) lacc[s] += comb[(64 + s) * 64 + l];

        // Vsum for masked-query rows (fp32 partials from prep)
        float vsum[4] = {0.f, 0.f, 0.f, 0.f};
        const float* vpb = Vpart + (size_t)(bh * 32) * 64;
        #pragma unroll 4
        for (int kt2 = 0; kt2 < 32; ++kt2) {
            #pragma unroll
            for (int n = 0; n < 4; ++n) vsum[n] += vpb[kt2 * 64 + n * 16 + lq];
        }

        const float inv2048 = 1.0f / 2048.0f;
        #pragma unroll
        for (int s = 0; s < 4; ++s) {
            float L = lacc[s];
            L += __shfl_xor(L, 16, 64);
            L += __shfl_xor(L, 32, 64);     // lane x holds L[q = x&15]
            const int4 mq4 = *(const int4*)&mask[b * Ss + q0 + s * 16 + lg * 4];
            const int mqa[4] = {mq4.x, mq4.y, mq4.z, mq4.w};
            #pragma unroll
            for (int r = 0; r < 4; ++r) {
                const float invl = 1.0f / __shfl(L, lg * 4 + r, 64);
                float* orow = out + (bhS + q0 + s * 16 + lg * 4 + r) * Dd + lq;
                #pragma unroll
                for (int n = 0; n < 4; ++n)
                    orow[16 * n] = mqa[r] ? Oacc[s][n][r] * invl : vsum[n] * inv2048;
            }
        }
    }
}

extern "C" void kernel_launch(void* const* d_in, const int* in_sizes, int n_in,
                              void* d_out, int out_size, void* d_ws, size_t ws_size,
                              hipStream_t stream) {
    const float* Q    = (const float*)d_in[0];
    const float* K    = (const float*)d_in[1];
    const float* V    = (const float*)d_in[2];
    const int*   mask = (const int*)d_in[3];
    float* out = (float*)d_out;

    ushort* Kf    = (ushort*)d_ws;                        // 8.39 MB
    ushort* Vf    = Kf + (size_t)4194304;                 // 8.39 MB
    float*  mb    = (float*)(Vf + (size_t)4194304);       // 16 KB
    float*  Vpart = mb + 4096;                            // 256 KB

    hipLaunchKernelGGL(prep_kernel, dim3(2049), dim3(256), 0, stream,
                       K, V, mask, Kf, Vf, mb, Vpart);
    hipLaunchKernelGGL(sdpa_main, dim3(1024), dim3(128), 0, stream,
                       Q, Kf, Vf, mb, Vpart, mask, out);
}

// Round 6
// 146.338 us; speedup vs baseline: 1.2989x; 1.2989x over previous
//
#include <hip/hip_runtime.h>

// SDPA B=2 H=16 S=2048 D=64 fp32. Two kernels.
//  prep: K,V -> fp16 in MFMA lane-order fragment layout (+ per-tile fp32 V
//        column sums Vpart); mask -> additive bias (-C2 / -1e30).
//  main R6: cooperative-block flash attention. 512-thr blocks = 8 waves;
//        wave w owns q-rows [qb*256+w*32, +32) x ALL 2048 keys -> denominator
//        wave-complete, NO K-split combine. All waves share one 32-key tile
//        per iteration from a 2-deep 16KB LDS buffer; staging one 8KB tile =
//        ONE global_load_lds per wave (8x1KB chunks). Counted vmcnt(3) (never
//        0 in-loop), raw s_barrier (no __syncthreads vmcnt(0) drain), asm
//        memory walls pin the 3-vmem-op issue groups. Grid 32bh x 8qb = 256
//        = exactly 1 block/CU: residency immune to VGPR tiers (<=256 ok) --
//        the cliff that killed R1/R2/R5 cannot fire. L2 reads 537->134 MB.
//        R0-R5 lessons: per-wave VGPR double-buffers spill (~210 live);
//        128-VGPR tier cliff at 4-wave blocks; sched_barrier over-pinning.
// Numerics: Q*scale*log2e folded in, fp16 QK, bias fed as MFMA C operand,
// raw v_exp_f32, v_cvt_pkrtz pack, L via VALU adds. Masked query -> out =
// Vsum/2048 from fp32 Vpart (reference's uniform-softmax branch).

#define Bb 2
#define Hh 16
#define Ss 2048
#define Dd 64

typedef __attribute__((ext_vector_type(8))) _Float16 f16x8;
typedef __attribute__((ext_vector_type(2))) __fp16 fp16x2;
typedef __attribute__((ext_vector_type(4))) float f32x4;

#define C2F (4.0f * 1.44269504088896340736f)
#define SCLF (0.125f * 1.44269504088896340736f)   // folded into Q

// ---------------- prepass ----------------
// Kf frag: id=((bh*32+kt)*8+slot)*64+lane, slot=T*2+c, lane=rl|(g<<4):
//   elem j = K[bh][kt*64+T*16+rl][c*32+g*8+j]
// Vf frag: slot=G*4+n, lane=m|(g<<4):
//   elem j = V[bh][kt*64+G*32+((j>>2)&1)*16+g*4+(j&3)][n*16+m]
__global__ __launch_bounds__(256) void prep_kernel(
    const float* __restrict__ K, const float* __restrict__ V,
    const int* __restrict__ mask,
    ushort* __restrict__ Kf, ushort* __restrict__ Vf,
    float* __restrict__ mb, float* __restrict__ Vpart)
{
    __shared__ ushort tile[4096];
    __shared__ float  part[16][64];
    const int t = threadIdx.x;
    const int blk = blockIdx.x;

    if (blk < 1024) {                       // ---- K tiles (LDS-staged, coalesced) ----
        const int bh = blk >> 5, kt = blk & 31;
        const float* base = K + ((size_t)bh * Ss + kt * 64) * Dd;
        #pragma unroll
        for (int i = 0; i < 4; ++i) {
            const int p  = i * 16 + (t >> 4);
            const int c0 = (t & 15) * 4;
            const float4 f = *(const float4*)(base + (size_t)p * Dd + c0);
            const int T = p >> 4, rl = p & 15;
            const int c = c0 >> 5, g = (c0 & 31) >> 3, j0 = c0 & 7;
            union { _Float16 h[4]; uint2 d; } pk;
            pk.h[0] = (_Float16)f.x; pk.h[1] = (_Float16)f.y;
            pk.h[2] = (_Float16)f.z; pk.h[3] = (_Float16)f.w;
            *(uint2*)&tile[((T * 2 + c) * 64 + (rl | (g << 4))) * 8 + j0] = pk.d;
        }
        __syncthreads();
        uint4* dst = (uint4*)(Kf + (size_t)(bh * 32 + kt) * 4096);
        const uint4* src = (const uint4*)tile;
        dst[t] = src[t]; dst[t + 256] = src[t + 256];
    } else if (blk < 2048) {                // ---- V tiles: register transpose + Vpart ----
        const int bv = blk - 1024;
        const int bh = bv >> 5, kt = bv & 31;
        const float* base = V + ((size_t)bh * Ss + kt * 64) * Dd;
        const int kb4 = (t >> 4) * 4;       // key base 0..60
        const int d0  = (t & 15) * 4;       // d base   0..60 (consecutive t -> coalesced)
        const float4 r0 = *(const float4*)(base + (size_t)(kb4 + 0) * Dd + d0);
        const float4 r1 = *(const float4*)(base + (size_t)(kb4 + 1) * Dd + d0);
        const float4 r2 = *(const float4*)(base + (size_t)(kb4 + 2) * Dd + d0);
        const float4 r3 = *(const float4*)(base + (size_t)(kb4 + 3) * Dd + d0);
        const int G = kb4 >> 5, p5 = kb4 & 31;
        const int tt = p5 >> 4, g = (p5 >> 2) & 3;
        const int j0 = tt * 4;
        const int n = d0 >> 4, m0 = d0 & 15;
        ushort* dstb = Vf + (size_t)(bh * 32 + kt) * 4096;
        const float ra[4][4] = {{r0.x, r1.x, r2.x, r3.x}, {r0.y, r1.y, r2.y, r3.y},
                                {r0.z, r1.z, r2.z, r3.z}, {r0.w, r1.w, r2.w, r3.w}};
        float4 ps;
        #pragma unroll
        for (int dd = 0; dd < 4; ++dd) {
            union { _Float16 h[4]; uint2 d; } pk;
            pk.h[0] = (_Float16)ra[dd][0]; pk.h[1] = (_Float16)ra[dd][1];
            pk.h[2] = (_Float16)ra[dd][2]; pk.h[3] = (_Float16)ra[dd][3];
            const int lane = (m0 + dd) | (g << 4);
            *(uint2*)&dstb[((G * 4 + n) * 64 + lane) * 8 + j0] = pk.d;
            ((float*)&ps)[dd] = (ra[dd][0] + ra[dd][1]) + (ra[dd][2] + ra[dd][3]);
        }
        *(float4*)&part[t >> 4][d0] = ps;   // fp32 partial column sums (4 keys)
        __syncthreads();
        if (t < 64) {
            float acc = 0.f;
            #pragma unroll
            for (int gg = 0; gg < 16; ++gg) acc += part[gg][t];
            Vpart[(size_t)(bh * 32 + kt) * 64 + t] = acc;
        }
    } else {                                // ---- mask -> bias ----
        #pragma unroll
        for (int i = 0; i < 16; ++i) {
            const int idx = i * 256 + t;
            mb[idx] = mask[idx] ? (-C2F) : -1e30f;
        }
    }
}

// async 16B/lane global->LDS (HW adds lane*16 to the wave-uniform LDS base)
static __device__ __forceinline__ void gll16(const void* g, ushort* l) {
    __builtin_amdgcn_global_load_lds(
        (const __attribute__((address_space(1))) void*)g,
        (__attribute__((address_space(3))) void*)l, 16, 0, 0);
}

// ---------------- main (cooperative 8-wave block, shared LDS tiles) ----------------
__global__ __launch_bounds__(512) void sdpa_main(
    const float* __restrict__ Q, const ushort* __restrict__ Kf,
    const ushort* __restrict__ Vf, const float* __restrict__ mbp,
    const float* __restrict__ Vpart,
    const int* __restrict__ mask, float* __restrict__ out)
{
    // shared 2-deep tile buffer: [buf][K 4KB | V 4KB] = 16 KB total.
    __shared__ ushort sbuf[2][4096];

    const int t  = threadIdx.x, w = t >> 6, l = t & 63;
    const int lq = l & 15, lg = l >> 4;
    const int bh = blockIdx.x & 31;         // XCD swizzle: one bh -> one L2
    const int qb = blockIdx.x >> 5;         // 0..7
    const int b  = bh >> 4;
    const int q0 = qb * 256 + w * 32;       // wave's 32 q-rows

    const size_t bhS = (size_t)bh * Ss;
    const ushort* kgb = Kf + (size_t)(bh * 32) * 4096;
    const ushort* vgb = Vf + (size_t)(bh * 32) * 4096;
    const float*  mbb = mbp + b * Ss;

    // staging role: wave w loads chunk w of each 8KB tile (1KB = 1 gll16)
    const char* sgb = (const char*)(w < 4 ? kgb : vgb) + (w & 3) * 1024 + l * 16;
    const int   sdoff = (w >> 2) * 2048 + (w & 3) * 512;   // ushort idx, uniform

    // ---- Q fragments: 2 subtiles, fp16, scale*log2e folded ----
    f16x8 qh[2][2];
    #pragma unroll
    for (int s = 0; s < 2; ++s) {
        const float* qrow = Q + (bhS + q0 + s * 16 + lq) * Dd + lg * 8;
        #pragma unroll
        for (int c = 0; c < 2; ++c) {
            const float4 f0 = *(const float4*)(qrow + 32 * c);
            const float4 f1 = *(const float4*)(qrow + 32 * c + 4);
            const float qf[8] = {f0.x, f0.y, f0.z, f0.w, f1.x, f1.y, f1.z, f1.w};
            union { _Float16 h[8]; f16x8 v; } pk;
            #pragma unroll
            for (int j = 0; j < 8; ++j) pk.h[j] = (_Float16)(qf[j] * SCLF);
            qh[s][c] = pk.v;
        }
    }

    f32x4 Oacc[2][4];
    float lacc[2] = {0.f, 0.f};
    #pragma unroll
    for (int s = 0; s < 2; ++s)
        #pragma unroll
        for (int n = 0; n < 4; ++n) Oacc[s][n] = f32x4{0.f, 0.f, 0.f, 0.f};

    #define WALL    asm volatile("" ::: "memory")
    #define WVC(n)  asm volatile("s_waitcnt vmcnt(" #n ")" ::: "memory")
    #define BAR     __builtin_amdgcn_s_barrier()

    // one gll16 per wave stages this wave's chunk of tile kk into buf
    #define STG(kk, bufsel)  gll16(sgb + (size_t)(kk) * 128, &sbuf[bufsel][sdoff])
    #define BIAS(kk, B0, B1) do {                                               \
        B0 = *(const float4*)(mbb + (kk) + lg * 4);                             \
        B1 = *(const float4*)(mbb + (kk) + 16 + lg * 4);                        \
    } while (0)

    #define LDKV(bufsel, KF, VF) do {                                           \
        const ushort* p_ = &sbuf[bufsel][l * 8];                                \
        KF[0] = *(const f16x8*)(p_);                                            \
        KF[1] = *(const f16x8*)(p_ + 512);                                      \
        KF[2] = *(const f16x8*)(p_ + 1024);                                     \
        KF[3] = *(const f16x8*)(p_ + 1536);                                     \
        VF[0] = *(const f16x8*)(p_ + 2048);                                     \
        VF[1] = *(const f16x8*)(p_ + 2560);                                     \
        VF[2] = *(const f16x8*)(p_ + 3072);                                     \
        VF[3] = *(const f16x8*)(p_ + 3584);                                     \
    } while (0)

    // one 32-key tile: QK (bias as MFMA C) -> exp -> L -> pack -> PV
    #define STEP(KF, VF, B0, B1) do {                                           \
        union { uint u32[4]; f16x8 v; } p8_[2];                                 \
        _Pragma("unroll")                                                       \
        for (int T_ = 0; T_ < 2; ++T_) {                                        \
            const f16x8 k0_ = KF[T_ * 2], k1_ = KF[T_ * 2 + 1];                 \
            const float4 bi_ = (T_ == 0) ? B0 : B1;                             \
            _Pragma("unroll")                                                   \
            for (int s_ = 0; s_ < 2; ++s_) {                                    \
                f32x4 sc_ = __builtin_amdgcn_mfma_f32_16x16x32_f16(             \
                    k0_, qh[s_][0], (f32x4){bi_.x, bi_.y, bi_.z, bi_.w}, 0, 0, 0); \
                sc_ = __builtin_amdgcn_mfma_f32_16x16x32_f16(k1_, qh[s_][1], sc_, 0, 0, 0); \
                const float e0_ = __builtin_amdgcn_exp2f(sc_[0]);               \
                const float e1_ = __builtin_amdgcn_exp2f(sc_[1]);               \
                const float e2_ = __builtin_amdgcn_exp2f(sc_[2]);               \
                const float e3_ = __builtin_amdgcn_exp2f(sc_[3]);               \
                lacc[s_] += (e0_ + e1_) + (e2_ + e3_);                          \
                union { fp16x2 h; uint u; } pa_, pb_;                           \
                pa_.h = __builtin_amdgcn_cvt_pkrtz(e0_, e1_);                   \
                pb_.h = __builtin_amdgcn_cvt_pkrtz(e2_, e3_);                   \
                p8_[s_].u32[T_ * 2]     = pa_.u;                                \
                p8_[s_].u32[T_ * 2 + 1] = pb_.u;                                \
            }                                                                   \
        }                                                                       \
        __builtin_amdgcn_s_setprio(1);                                          \
        _Pragma("unroll")                                                       \
        for (int n_ = 0; n_ < 4; ++n_) {                                        \
            const f16x8 vf_ = VF[n_];                                           \
            _Pragma("unroll")                                                   \
            for (int s_ = 0; s_ < 2; ++s_)                                      \
                Oacc[s_][n_] = __builtin_amdgcn_mfma_f32_16x16x32_f16(p8_[s_].v, vf_, Oacc[s_][n_], 0, 0, 0); \
        }                                                                       \
        __builtin_amdgcn_s_setprio(0);                                          \
    } while (0)

    f16x8 kf[4], vf[4];
    float4 a0, a1, b0, b1;

    // ---- prologue: tiles 0 (buf0) and 1 (buf1); vmem groups pinned by walls:
    // [S0, b0 x2][S1, b1 x2] -> 6 outstanding entering the loop.
    WALL;
    STG(0, 0);  BIAS(0, a0, a1);  WALL;
    STG(32, 1); BIAS(32, b0, b1); WALL;

    // ---- K-loop: 64 tiles, unrolled x2. Per tile: wait own 3 oldest vmem
    // (tile t's stage+bias landed), barrier (ALL waves' chunks landed),
    // ds_read+compute, barrier (all done reading), stage tile t+2 (3 vmem).
    // vmcnt never drains below 3 until the last tile.
    for (int tt = 0; tt < 62; tt += 2) {
        const int kk = tt * 32;
        // tile tt (buf0, biasA)
        WVC(3); BAR; WALL;
        LDKV(0, kf, vf);
        STEP(kf, vf, a0, a1);
        WALL; BAR; WALL;
        STG(kk + 64, 0); BIAS(kk + 64, a0, a1); WALL;
        // tile tt+1 (buf1, biasB)
        WVC(3); BAR; WALL;
        LDKV(1, kf, vf);
        STEP(kf, vf, b0, b1);
        WALL; BAR; WALL;
        STG(kk + 96, 1); BIAS(kk + 96, b0, b1); WALL;
    }
    // tile 62 (buf0): outstanding = {S62,b62x2,S63,b63x2} -> WVC(3)
    WVC(3); BAR; WALL;
    LDKV(0, kf, vf);
    STEP(kf, vf, a0, a1);
    WALL; BAR; WALL;
    // tile 63 (buf1): drain
    WVC(0); BAR; WALL;
    LDKV(1, kf, vf);
    STEP(kf, vf, b0, b1);

    #undef WALL
    #undef WVC
    #undef BAR
    #undef STG
    #undef BIAS
    #undef LDKV
    #undef STEP

    // ---- epilogue: wave-complete rows, no combine ----
    // Vsum for masked-query rows (fp32 partials from prep)
    float vsum[4] = {0.f, 0.f, 0.f, 0.f};
    const float* vpb = Vpart + (size_t)(bh * 32) * 64;
    #pragma unroll 4
    for (int kt2 = 0; kt2 < 32; ++kt2) {
        #pragma unroll
        for (int n = 0; n < 4; ++n) vsum[n] += vpb[kt2 * 64 + n * 16 + lq];
    }

    const float inv2048 = 1.0f / 2048.0f;
    #pragma unroll
    for (int s = 0; s < 2; ++s) {
        float L = lacc[s];
        L += __shfl_xor(L, 16, 64);
        L += __shfl_xor(L, 32, 64);         // lane x holds L[q = x&15]
        const int4 mq4 = *(const int4*)&mask[b * Ss + q0 + s * 16 + lg * 4];
        const int mqa[4] = {mq4.x, mq4.y, mq4.z, mq4.w};
        #pragma unroll
        for (int r = 0; r < 4; ++r) {
            const float invl = 1.0f / __shfl(L, lg * 4 + r, 64);
            float* orow = out + (bhS + q0 + s * 16 + lg * 4 + r) * Dd + lq;
            #pragma unroll
            for (int n = 0; n < 4; ++n)
                orow[16 * n] = mqa[r] ? Oacc[s][n][r] * invl : vsum[n] * inv2048;
        }
    }
}

extern "C" void kernel_launch(void* const* d_in, const int* in_sizes, int n_in,
                              void* d_out, int out_size, void* d_ws, size_t ws_size,
                              hipStream_t stream) {
    const float* Q    = (const float*)d_in[0];
    const float* K    = (const float*)d_in[1];
    const float* V    = (const float*)d_in[2];
    const int*   mask = (const int*)d_in[3];
    float* out = (float*)d_out;

    ushort* Kf    = (ushort*)d_ws;                        // 8.39 MB
    ushort* Vf    = Kf + (size_t)4194304;                 // 8.39 MB
    float*  mb    = (float*)(Vf + (size_t)4194304);       // 16 KB
    float*  Vpart = mb + 4096;                            // 256 KB

    hipLaunchKernelGGL(prep_kernel, dim3(2049), dim3(256), 0, stream,
                       K, V, mask, Kf, Vf, mb, Vpart);
    hipLaunchKernelGGL(sdpa_main, dim3(256), dim3(512), 0, stream,
                       Q, Kf, Vf, mb, Vpart, mask, out);
}